// Round 8
// baseline (24.616 us; speedup 1.0000x reference)
//
#include <hip/hip_runtime.h>

// LogitDistance: out = sum_b sum_{i<j} |p[b,i]-p[b,j]| / (ntriu * B * N)
//
// Sort-based exact algorithm (leaves the 2-op/pair class, ~2us total VALU):
//  k1: each wave sorts one 64-elem segment (bitonic via shfl_xor),
//      within-segment pair sum = sum_k (2k-63) x_(k)  [exact, tie-safe],
//      stores sorted segment + per-wave partial.
//  k2: 2016 segment-pairs/row x 16 rows = 32256 merge tasks, 8 per wave.
//      For sorted A,B: sum|a-b| = sum_a [(2c-64)a + S_B - 2P_c],
//      c = #{b < a} (7-step LDS lower_bound), P = shfl-scan prefix.
//      Equal elements contribute 0 either side -> exact with ties.
//      Coverage: 64*C(64,2) + 2016*4096 = C(4096,2) per row, each pair once.
//  k3: one wave, fixed-order f64 reduce of 2032 partials, scale, store.
// No atomics, no fences, no memsets; ws fully overwritten every call.

#define NN   4096
#define SEG  64
#define SPR  64        // segments per row
#define TPRW 2016      // cross tasks per row = C(64,2)
#define WPRW 252       // k2 waves per row (8 tasks each)

__global__ __launch_bounds__(256) void k1_sortseg(
    const float* __restrict__ pred, float* __restrict__ sorted,
    float* __restrict__ part)
{
    const int lane = threadIdx.x & 63;
    const int wid  = threadIdx.x >> 6;
    const int g    = blockIdx.x * 4 + wid;       // segment id = row*64+seg
    const int row  = g >> 6;
    const int seg  = g & 63;

    float v = pred[(row << 12) + (seg << 6) + lane];

    // bitonic sort ascending across the 64-lane wave
#pragma unroll
    for (int k = 2; k <= 64; k <<= 1) {
#pragma unroll
        for (int j = k >> 1; j >= 1; j >>= 1) {
            float o = __shfl_xor(v, j, 64);
            bool up = ((lane & k) == 0) || (k == 64);  // final merge ascending
            bool hi = (lane & j) != 0;
            v = (hi == up) ? fmaxf(v, o) : fminf(v, o);
        }
    }

    sorted[(g << 6) + lane] = v;

    // within-segment pair sum: sum_k (2k - 63) * x_(k)
    float t = (float)(2 * lane - 63) * v;
#pragma unroll
    for (int off = 32; off > 0; off >>= 1)
        t += __shfl_down(t, off, 64);
    if (lane == 0) part[g] = t;
}

__global__ __launch_bounds__(256) void k2_cross(
    const float* __restrict__ sorted, float* __restrict__ part)
{
    __shared__ float sb[4][SEG];
    __shared__ float sp[4][SEG];
    __shared__ float cw[4];

    const int lane = threadIdx.x & 63;
    const int wid  = threadIdx.x >> 6;
    const int wg   = blockIdx.x * 4 + wid;       // 0 .. B*252-1
    const int row  = wg / WPRW;
    const int q0   = (wg % WPRW) * 8;

    float acc = 0.0f;

#pragma unroll 2
    for (int it = 0; it < 8; ++it) {
        const int t = q0 + it;                   // 0 .. 2015
        int s1, s2;
        if (t < 1984) {                          // d in [1,31]
            const int d = 1 + (t >> 6);
            s1 = t & 63;
            s2 = (s1 + d) & 63;
        } else {                                 // d == 32 (32 pairs)
            s1 = t - 1984;
            s2 = s1 + 32;
        }
        const float a = sorted[(((size_t)row << 6) + s1) * SEG + lane];
        const float b = sorted[(((size_t)row << 6) + s2) * SEG + lane];

        // inclusive shfl-scan of sorted b -> prefix sums
        float inc = b;
#pragma unroll
        for (int j = 1; j < 64; j <<= 1) {
            float u = __shfl_up(inc, j, 64);
            if (lane >= j) inc += u;
        }
        const float SB = __shfl(inc, 63, 64);
        sb[wid][lane] = b;
        sp[wid][lane] = inc - b;                 // exclusive prefix
        // same-wave LDS write->read: in-order, no barrier needed

        // c = #{b < a} via branchless lower_bound (7 probes)
        int c = 0;
#pragma unroll
        for (int step = 32; step >= 1; step >>= 1)
            if (sb[wid][c + step - 1] < a) c += step;   // c <= 63 here
        if (sb[wid][c] < a) ++c;                        // c in [0,64]

        const float Pc = (c < 64) ? sp[wid][c] : SB;
        // sum_b |a-b| contribution of this lane's a:
        acc += (2.0f * (float)c - 64.0f) * a + SB - 2.0f * Pc;
    }

#pragma unroll
    for (int off = 32; off > 0; off >>= 1)
        acc += __shfl_down(acc, off, 64);

    if (lane == 0) cw[wid] = acc;
    __syncthreads();
    if (threadIdx.x == 0)
        part[blockIdx.x] = (cw[0] + cw[1]) + (cw[2] + cw[3]);  // fixed order
}

// one wave: fixed-order f64 reduce of npart partials
__global__ __launch_bounds__(64) void k3_fin(
    const float* __restrict__ part, int npart,
    float* __restrict__ out, double scale)
{
    double s = 0.0;
    for (int i = threadIdx.x; i < npart; i += 64)
        s += (double)part[i];
#pragma unroll
    for (int off = 32; off > 0; off >>= 1)
        s += __shfl_down(s, off, 64);
    if (threadIdx.x == 0) out[0] = (float)(s * scale);
}

extern "C" void kernel_launch(void* const* d_in, const int* in_sizes, int n_in,
                              void* d_out, int out_size, void* d_ws, size_t ws_size,
                              hipStream_t stream) {
    const float* pred = (const float*)d_in[0];
    const int total = in_sizes[0];
    const int B = total / NN;                    // 16

    const int nseg     = B * SPR;                // 1024 segments
    const int k1_blks  = nseg / 4;               // 256
    const int k2_blks  = B * WPRW / 4;           // 1008
    const int npart    = nseg + k2_blks;         // 2032

    float* sorted = (float*)d_ws;                          // nseg*64 floats
    float* part   = sorted + (size_t)nseg * SEG;           // npart floats
    float* wpart  = part;                                  // k1: [0, nseg)
    float* cpart  = part + nseg;                           // k2: [nseg, npart)

    k1_sortseg<<<k1_blks, 256, 0, stream>>>(pred, sorted, wpart);
    k2_cross  <<<k2_blks, 256, 0, stream>>>(sorted, cpart);

    const double ntriu = (double)NN * (double)(NN - 1) * 0.5;
    const double scale = 1.0 / (ntriu * (double)B * (double)NN);
    k3_fin<<<1, 64, 0, stream>>>(part, npart, (float*)d_out, scale);
}

// Round 9
// 18.265 us; speedup vs baseline: 1.3477x; 1.3477x over previous
//
#include <hip/hip_runtime.h>

// LogitDistance: out = sum_b sum_{i<j} |p[b,i]-p[b,j]| / (ntriu * B * N)
//
// SINGLE dispatch, fused reduce via tagged slots (round-7 pattern, tail-
// trimmed): 544 compute blocks x 512 thr (8 waves, one exact triangle
// unit each: 256-i x 128-j, jh>=2c, w=0.5 iff j-seg inside i-chunk).
// 8-wave LDS combine -> ONE 8-byte relaxed agent-scope atomic store of
// (f32 partial | MAGIC tag) per block (tag+value travel together -> no
// fences, no RMW atomics, no memsets). Block 0 wave 0: each lane WAITS
// IN FIXED ORDER on its 8-9 slots, accumulating as they land (order is
// per-lane static -> bit-deterministic), f64 butterfly, scale, store,
// clear tags for next replay (poisoned ws tag 0xAAAAAAAA != MAGIC).
// Compute blocks never wait -> no deadlock, no co-residency requirement.

#define NN      4096
#define THREADS 512
#define WAVES   8
#define R       4      // i-values per lane
#define CSZ     256    // i-chunk width
#define JSEG    128    // j-values staged per wave
#define BPR     34     // compute blocks per batch row (272 units / 8 waves)
#define NSLOT   544    // 16 rows * 34 blocks
#define MAGIC   0x7F3A9C51u

__global__ __launch_bounds__(THREADS) void pairdist_fused(
    const float* __restrict__ pred,
    unsigned long long* __restrict__ slots,
    float* __restrict__ out, double scale)
{
    if (blockIdx.x == 0) {
        // ---------------- reducer: one wave ----------------
        if (threadIdx.x >= 64) return;
        const int l = threadIdx.x;
        double s = 0.0;
        // fixed per-lane slot order; accumulate as each lands (deterministic)
#pragma unroll
        for (int k = 0; k < 9; ++k) {
            const int idx = l + 64 * k;
            if (idx < NSLOT) {
                unsigned long long p;
                for (;;) {
                    p = __hip_atomic_load(&slots[idx], __ATOMIC_RELAXED,
                                          __HIP_MEMORY_SCOPE_AGENT);
                    if ((unsigned)(p >> 32) == MAGIC) break;
                    __builtin_amdgcn_s_sleep(1);
                }
                s += (double)__uint_as_float((unsigned)p);
            }
        }
#pragma unroll
        for (int off = 32; off > 0; off >>= 1)
            s += __shfl_down(s, off, 64);                    // fixed order
        if (l == 0) out[0] = (float)(s * scale);
        // clear tags so the next replay starts untagged
#pragma unroll
        for (int k = 0; k < 9; ++k) {
            const int idx = l + 64 * k;
            if (idx < NSLOT) {
                unsigned* tag = ((unsigned*)&slots[idx]) + 1;
                __hip_atomic_store(tag, 0u, __ATOMIC_RELAXED,
                                   __HIP_MEMORY_SCOPE_AGENT);
            }
        }
        return;
    }

    // ---------------- compute blocks ----------------
    const int cb   = blockIdx.x - 1;            // 0..543
    const int lane = threadIdx.x & 63;
    const int wid  = threadIdx.x >> 6;
    const int b    = cb / BPR;
    int u = (cb % BPR) * WAVES + wid;           // 0..271

    // decode u -> (c, jh, w): for c in 0..15, jh in [2c, 32)
    int c = 0;
    while (u >= 32 - 2 * c) { u -= 32 - 2 * c; ++c; }
    const int   jh = 2 * c + u;
    const float w  = (u < 2) ? 0.5f : 1.0f;

    const float* __restrict__ row = pred + (size_t)b * NN;

    __shared__ float sj[WAVES][JSEG];   // wave-private slices: no barrier
    __shared__ float sw[WAVES];
    sj[wid][lane]      = row[jh * JSEG + lane];
    sj[wid][64 + lane] = row[jh * JSEG + 64 + lane];

    float pi[R];
#pragma unroll
    for (int k = 0; k < R; ++k)
        pi[k] = row[c * CSZ + k * 64 + lane];

    float a0 = 0.f, a1 = 0.f, a2 = 0.f, a3 = 0.f;
#pragma unroll 8
    for (int j = 0; j < JSEG; j += 4) {
        float4 jv = *reinterpret_cast<const float4*>(&sj[wid][j]);
        a0 += fabsf(pi[0] - jv.x); a1 += fabsf(pi[1] - jv.x);
        a2 += fabsf(pi[2] - jv.x); a3 += fabsf(pi[3] - jv.x);
        a0 += fabsf(pi[0] - jv.y); a1 += fabsf(pi[1] - jv.y);
        a2 += fabsf(pi[2] - jv.y); a3 += fabsf(pi[3] - jv.y);
        a0 += fabsf(pi[0] - jv.z); a1 += fabsf(pi[1] - jv.z);
        a2 += fabsf(pi[2] - jv.z); a3 += fabsf(pi[3] - jv.z);
        a0 += fabsf(pi[0] - jv.w); a1 += fabsf(pi[1] - jv.w);
        a2 += fabsf(pi[2] - jv.w); a3 += fabsf(pi[3] - jv.w);
    }
    float s = (a0 + a1) + (a2 + a3);

#pragma unroll
    for (int off = 32; off > 0; off >>= 1)
        s += __shfl_down(s, off, 64);

    if (lane == 0) sw[wid] = s * w;
    __syncthreads();

    if (threadIdx.x == 0) {
        float bs = ((sw[0] + sw[1]) + (sw[2] + sw[3])) +
                   ((sw[4] + sw[5]) + (sw[6] + sw[7]));   // fixed order
        unsigned long long p = ((unsigned long long)MAGIC << 32) |
                               (unsigned long long)__float_as_uint(bs);
        __hip_atomic_store(&slots[cb], p, __ATOMIC_RELAXED,
                           __HIP_MEMORY_SCOPE_AGENT);
    }
}

extern "C" void kernel_launch(void* const* d_in, const int* in_sizes, int n_in,
                              void* d_out, int out_size, void* d_ws, size_t ws_size,
                              hipStream_t stream) {
    const float* pred = (const float*)d_in[0];
    const int total = in_sizes[0];
    const int B = total / NN;                    // 16
    const int nblocks = 1 + B * BPR;             // 545 (block 0 = reducer)

    unsigned long long* slots = (unsigned long long*)d_ws;  // 544 * 8 B

    const double ntriu = (double)NN * (double)(NN - 1) * 0.5;
    const double scale = 1.0 / (ntriu * (double)B * (double)NN);

    pairdist_fused<<<nblocks, THREADS, 0, stream>>>(
        pred, slots, (float*)d_out, scale);
}